// Round 1
// baseline (223.323 us; speedup 1.0000x reference)
//
#include <hip/hip_runtime.h>
#include <stdint.h>

typedef uint32_t u32;
typedef unsigned long long u64;

#define WGATES 32768
#define BATCH  128
#define LAYERS 32
#define NTYPES 16

// ---------------------------------------------------------------------------
// Kernel 1: pack h0 (feature rows [0,W)) into bitmasks, copy h0 floats to out,
// and pack the 16 activation truth tables into 16-bit masks.
// Thread t <-> (gate w = t>>7, batch b = t&127). One wave = 64 consecutive b
// of one gate -> __ballot gives a u64 = packed words [b0/32, b0/32+1].
// ---------------------------------------------------------------------------
__global__ void pack_kernel(const float* __restrict__ feature,
                            const float* __restrict__ activation,
                            float* __restrict__ out,
                            u32* __restrict__ tt_ws,
                            u32* __restrict__ buf0) {
    int t = blockIdx.x * 256 + threadIdx.x;
    if (blockIdx.x == 0 && threadIdx.x < NTYPES) {
        u32 tt = 0;
        #pragma unroll
        for (int m = 0; m < 16; ++m)
            tt |= (activation[threadIdx.x * 16 + m] != 0.0f ? 1u : 0u) << m;
        tt_ws[threadIdx.x] = tt;
    }
    float v = feature[t];
    out[t] = v;                       // h0 rows of the output, exact copy
    u64 m = __ballot(v != 0.0f);
    if ((t & 63) == 0)
        ((u64*)buf0)[t >> 6] = m;     // u64 index = w*2 + b0/64
}

// ---------------------------------------------------------------------------
// Kernel 2 (x32): one layer. Thread = (gate w, word q): word q holds batch
// bits 32q..32q+31. Gather 4 source words, evaluate the 16-bit LUT as a
// 4-level bitwise mux tree, store packed next state, then write the 16.8 MB
// float block for this layer with fully coalesced float4 stores via LDS.
// Block = 256 threads = 64 gates; grid = W/64 = 512 blocks.
// ---------------------------------------------------------------------------
__global__ void layer_kernel(const u32* __restrict__ prev,
                             u32* __restrict__ next,
                             const int* __restrict__ src_idx,   // + l*W*4
                             const int* __restrict__ cell_type, // + l*W
                             const u32* __restrict__ tt_ws,
                             float* __restrict__ out)           // + (l+1)*W*B
{
    __shared__ u32 lds_tt[NTYPES];
    __shared__ u32 lds_pack[256];     // 64 gates x 4 words
    int tid = threadIdx.x;
    if (tid < NTYPES) lds_tt[tid] = tt_ws[tid];

    int gl = tid >> 2;                // local gate 0..63
    int q  = tid & 3;                 // batch word 0..3
    int wg = blockIdx.x * 64 + gl;

    const int4 s = ((const int4*)src_idx)[wg];
    int ct = cell_type[wg];
    __syncthreads();
    u32 tt = lds_tt[ct];

    u32 a = prev[(size_t)s.x * 4 + q];
    u32 b = prev[(size_t)s.y * 4 + q];
    u32 c = prev[(size_t)s.z * 4 + q];
    u32 d = prev[(size_t)s.w * 4 + q];

    // 16 truth-table bits -> full masks (sign-extend trick), then mux tree.
    u32 m[16];
    #pragma unroll
    for (int j = 0; j < 16; ++j)
        m[j] = (u32)(((int)(tt << (31 - j))) >> 31);
    u32 na = ~a, nb = ~b, nc = ~c, nd = ~d;
    u32 v0 = (m[1]&a)|(m[0]&na),  v1 = (m[3]&a)|(m[2]&na);
    u32 v2 = (m[5]&a)|(m[4]&na),  v3 = (m[7]&a)|(m[6]&na);
    u32 v4 = (m[9]&a)|(m[8]&na),  v5 = (m[11]&a)|(m[10]&na);
    u32 v6 = (m[13]&a)|(m[12]&na),v7 = (m[15]&a)|(m[14]&na);
    u32 u0 = (b&v1)|(nb&v0), u1 = (b&v3)|(nb&v2);
    u32 u2 = (b&v5)|(nb&v4), u3 = (b&v7)|(nb&v6);
    u32 w0 = (c&u1)|(nc&u0), w1 = (c&u3)|(nc&u2);
    u32 r  = (d&w1)|(nd&w0);

    next[(size_t)wg * 4 + q] = r;     // coalesced: tid -> consecutive words
    lds_pack[tid] = r;
    __syncthreads();

    // Unpack block's 64 gates * 128 floats = 8192 floats, 8 coalesced rounds.
    float4* obase = (float4*)(out + (size_t)blockIdx.x * 8192);
    #pragma unroll
    for (int it = 0; it < 8; ++it) {
        int fidx = it * 1024 + tid * 4;       // float index in block region
        int g2   = fidx >> 7;                 // local gate
        int bit  = fidx & 127;                // batch element of .x
        u32 wb   = lds_pack[g2 * 4 + (bit >> 5)];
        int sh   = bit & 31;                  // multiple of 4, sh+3 <= 31
        float4 f;
        f.x = ((wb >> (sh    )) & 1) ? 1.0f : 0.0f;
        f.y = ((wb >> (sh + 1)) & 1) ? 1.0f : 0.0f;
        f.z = ((wb >> (sh + 2)) & 1) ? 1.0f : 0.0f;
        f.w = ((wb >> (sh + 3)) & 1) ? 1.0f : 0.0f;
        obase[fidx >> 2] = f;
    }
}

extern "C" void kernel_launch(void* const* d_in, const int* in_sizes, int n_in,
                              void* d_out, int out_size, void* d_ws, size_t ws_size,
                              hipStream_t stream) {
    const float* feature    = (const float*)d_in[0];
    const float* activation = (const float*)d_in[1];
    const int*   src_idx    = (const int*)d_in[2];
    const int*   cell_type  = (const int*)d_in[3];
    // d_in[4] = pins, constant [1,2,3,4] per setup -> weights 1,2,4,8 baked in.
    float* out = (float*)d_out;

    u32* tt_ws = (u32*)d_ws;                                   // 64 B
    u32* buf0  = (u32*)((char*)d_ws + 1024);                   // 512 KB
    u32* buf1  = (u32*)((char*)d_ws + 1024 + WGATES * 16);     // 512 KB

    pack_kernel<<<WGATES * BATCH / 256, 256, 0, stream>>>(
        feature, activation, out, tt_ws, buf0);

    for (int l = 0; l < LAYERS; ++l) {
        u32* prev = (l & 1) ? buf1 : buf0;
        u32* next = (l & 1) ? buf0 : buf1;
        layer_kernel<<<WGATES / 64, 256, 0, stream>>>(
            prev, next,
            src_idx + (size_t)l * WGATES * 4,
            cell_type + (size_t)l * WGATES,
            tt_ws,
            out + (size_t)(l + 1) * WGATES * BATCH);
    }
}

// Round 2
// 207.194 us; speedup vs baseline: 1.0778x; 1.0778x over previous
//
#include <hip/hip_runtime.h>
#include <stdint.h>

typedef uint32_t u32;
typedef unsigned long long u64;

#define WGATES 32768
#define BATCH  128
#define LAYERS 32
#define NTYPES 16
#define NB_COMPUTE 512      // 64 gates/block * 4 words
#define NB_UNPACK  2048     // 2048 blocks * 256 thr * 2 rounds * float4 = 16.78 MB

// ---------------------------------------------------------------------------
// Kernel 1: pack h0 (feature rows [0,W)) into bitmasks, copy h0 floats to out,
// and pack the 16 activation truth tables into 16-bit masks.
// ---------------------------------------------------------------------------
__global__ void pack_kernel(const float* __restrict__ feature,
                            const float* __restrict__ activation,
                            float* __restrict__ out,
                            u32* __restrict__ tt_ws,
                            u32* __restrict__ buf0) {
    int t = blockIdx.x * 256 + threadIdx.x;
    if (blockIdx.x == 0 && threadIdx.x < NTYPES) {
        u32 tt = 0;
        #pragma unroll
        for (int m = 0; m < 16; ++m)
            tt |= (activation[threadIdx.x * 16 + m] != 0.0f ? 1u : 0u) << m;
        tt_ws[threadIdx.x] = tt;
    }
    float v = feature[t];
    out[t] = v;                       // h0 rows of the output, exact copy
    u64 m = __ballot(v != 0.0f);
    if ((t & 63) == 0)
        ((u64*)buf0)[t >> 6] = m;     // u64 index = w*2 + b0/64
}

// ---------------------------------------------------------------------------
// Fused layer kernel: role A (blocks [0,512)) computes packed S_l from S_{l-1};
// role B (blocks [512,512+2048)) unpacks S_{l-1} (complete at kernel entry)
// into its float output block. Disjoint data -> full overlap of latency-bound
// gather work with BW-bound unpack stores.
// ---------------------------------------------------------------------------
__global__ void fused_kernel(const u32* __restrict__ prev,
                             u32* __restrict__ next,
                             const int* __restrict__ src_idx,   // layer's W*4
                             const int* __restrict__ cell_type, // layer's W
                             const u32* __restrict__ tt_ws,
                             const u32* __restrict__ upacked,   // = S_{l-1}
                             float* __restrict__ uout,          // float block, or null
                             int do_compute)
{
    int tid = threadIdx.x;
    if (do_compute && blockIdx.x < NB_COMPUTE) {
        // ---- compute role: thread = (gate, batch-word q) ----
        int gl = tid >> 2;                // local gate 0..63
        int q  = tid & 3;                 // batch word 0..3
        int wg = blockIdx.x * 64 + gl;

        const int4 s = ((const int4*)src_idx)[wg];
        u32 tt = tt_ws[cell_type[wg]];

        u32 a = prev[(size_t)s.x * 4 + q];
        u32 b = prev[(size_t)s.y * 4 + q];
        u32 c = prev[(size_t)s.z * 4 + q];
        u32 d = prev[(size_t)s.w * 4 + q];

        u32 m[16];
        #pragma unroll
        for (int j = 0; j < 16; ++j)
            m[j] = (u32)(((int)(tt << (31 - j))) >> 31);
        u32 na = ~a, nb = ~b, nc = ~c, nd = ~d;
        u32 v0 = (m[1]&a)|(m[0]&na),  v1 = (m[3]&a)|(m[2]&na);
        u32 v2 = (m[5]&a)|(m[4]&na),  v3 = (m[7]&a)|(m[6]&na);
        u32 v4 = (m[9]&a)|(m[8]&na),  v5 = (m[11]&a)|(m[10]&na);
        u32 v6 = (m[13]&a)|(m[12]&na),v7 = (m[15]&a)|(m[14]&na);
        u32 u0 = (b&v1)|(nb&v0), u1 = (b&v3)|(nb&v2);
        u32 u2 = (b&v5)|(nb&v4), u3 = (b&v7)|(nb&v6);
        u32 w0 = (c&u1)|(nc&u0), w1 = (c&u3)|(nc&u2);
        u32 r  = (d&w1)|(nd&w0);

        next[(size_t)wg * 4 + q] = r;     // coalesced packed store
        return;
    }

    // ---- unpack role ----
    if (uout == nullptr) return;
    int ub = do_compute ? (int)blockIdx.x - NB_COMPUTE : (int)blockIdx.x;

    #pragma unroll
    for (int r = 0; r < 2; ++r) {
        int fi  = ((ub * 2 + r) * 256 + tid) * 4;  // float idx in [0, W*B)
        int g   = fi >> 7;                         // gate
        int bit = fi & 127;                        // batch element of .x
        u32 wb  = upacked[g * 4 + (bit >> 5)];     // L2-hot, wave-broadcast
        int sh  = bit & 31;                        // multiple of 4
        float4 f;
        f.x = ((wb >> (sh    )) & 1) ? 1.0f : 0.0f;
        f.y = ((wb >> (sh + 1)) & 1) ? 1.0f : 0.0f;
        f.z = ((wb >> (sh + 2)) & 1) ? 1.0f : 0.0f;
        f.w = ((wb >> (sh + 3)) & 1) ? 1.0f : 0.0f;
        ((float4*)uout)[fi >> 2] = f;              // fully coalesced
    }
}

extern "C" void kernel_launch(void* const* d_in, const int* in_sizes, int n_in,
                              void* d_out, int out_size, void* d_ws, size_t ws_size,
                              hipStream_t stream) {
    const float* feature    = (const float*)d_in[0];
    const float* activation = (const float*)d_in[1];
    const int*   src_idx    = (const int*)d_in[2];
    const int*   cell_type  = (const int*)d_in[3];
    // d_in[4] = pins, constant [1,2,3,4] per setup -> weights 1,2,4,8 baked in.
    float* out = (float*)d_out;

    u32* tt_ws = (u32*)d_ws;                                   // 64 B
    u32* bufA  = (u32*)((char*)d_ws + 1024);                   // 512 KB
    u32* bufB  = (u32*)((char*)d_ws + 1024 + WGATES * 16);     // 512 KB

    pack_kernel<<<WGATES * BATCH / 256, 256, 0, stream>>>(
        feature, activation, out, tt_ws, bufA);

    for (int l = 1; l <= LAYERS; ++l) {
        u32* prev = ((l - 1) & 1) ? bufB : bufA;   // S_{l-1}
        u32* next = ((l - 1) & 1) ? bufA : bufB;   // S_l
        float* uout = (l >= 2) ? out + (size_t)(l - 1) * WGATES * BATCH : nullptr;
        fused_kernel<<<NB_COMPUTE + NB_UNPACK, 256, 0, stream>>>(
            prev, next,
            src_idx + (size_t)(l - 1) * WGATES * 4,
            cell_type + (size_t)(l - 1) * WGATES,
            tt_ws,
            prev,            // unpack source = S_{l-1}
            uout,
            1);
    }
    // Final: unpack-only for S_32 -> output block 32.
    u32* s32 = ((LAYERS - 1) & 1) ? bufA : bufB;   // buffer written at l=32
    fused_kernel<<<NB_UNPACK, 256, 0, stream>>>(
        s32, s32, src_idx, cell_type, tt_ws,
        s32, out + (size_t)LAYERS * WGATES * BATCH, 0);
}